// Round 3
// baseline (114.892 us; speedup 1.0000x reference)
//
#include <hip/hip_runtime.h>
#include <math.h>

#define N 1024
#define D 512
#define NC 16

static constexpr float THRESH    = 0.5f;
static constexpr float MARGIN    = 0.1f;
static constexpr float SCALE_POS = 0.05f;
static constexpr float SCALE_NEG = 0.002f;
static constexpr float EPS_      = 1e-5f;

typedef __bf16 bf16x8 __attribute__((ext_vector_type(8)));
typedef float  f32x4  __attribute__((ext_vector_type(4)));
typedef unsigned short ushort8v __attribute__((ext_vector_type(8)));

__device__ __forceinline__ unsigned short f2bf_rne(float x) {
    unsigned u = __builtin_bit_cast(unsigned, x);
    return (unsigned short)((u + 0x7FFFu + ((u >> 16) & 1u)) >> 16);
}

// ---------------------------------------------------------------------------
// Kernel 0: fp32 -> bf16 convert (8/thread) + label bit-pack + zero accums
// ---------------------------------------------------------------------------
__global__ __launch_bounds__(256) void prep(const float* __restrict__ F,
                                            const int* __restrict__ labels,
                                            unsigned short* __restrict__ Fb,
                                            unsigned* __restrict__ mask,
                                            double* __restrict__ loss_acc,
                                            int* __restrict__ total,
                                            unsigned* __restrict__ arrive) {
    const int idx = blockIdx.x * 256 + threadIdx.x;   // 65536 threads

    if (idx == 0) {               // zero accumulators (read only by later kernels)
        *loss_acc = 0.0;
        *total    = 0;
        *arrive   = 0u;
    }

    // --- convert 8 floats ---
    const float4* src = (const float4*)F;
    float4 v0 = src[idx * 2];
    float4 v1 = src[idx * 2 + 1];
    ushort8v o;
    o[0] = f2bf_rne(v0.x); o[1] = f2bf_rne(v0.y);
    o[2] = f2bf_rne(v0.z); o[3] = f2bf_rne(v0.w);
    o[4] = f2bf_rne(v1.x); o[5] = f2bf_rne(v1.y);
    o[6] = f2bf_rne(v1.z); o[7] = f2bf_rne(v1.w);
    *(ushort8v*)(Fb + idx * 8) = o;

    // --- pack labels (first 1024 threads) ---
    if (idx < N) {
        const int4* lp = (const int4*)(labels + idx * NC);
        unsigned m = 0;
        #pragma unroll
        for (int q = 0; q < 4; ++q) {
            int4 l4 = lp[q];
            if (l4.x == 1) m |= 1u << (q * 4 + 0);
            if (l4.y == 1) m |= 1u << (q * 4 + 1);
            if (l4.z == 1) m |= 1u << (q * 4 + 2);
            if (l4.w == 1) m |= 1u << (q * 4 + 3);
        }
        mask[idx] = m;
    }
}

// ---------------------------------------------------------------------------
// Kernel 1: sim = Fb * Fb^T via MFMA bf16, no LDS (both frags load contiguous)
// block: 256 thr = 4 waves; tile 64x64; wave w -> m-strip [16w,16w+16) x 64 n
// Diagonal pinned to 1.0f (matches fp32 reference's self-sim, which is
// always excluded from positives by the 1-eps test).
// ---------------------------------------------------------------------------
__global__ __launch_bounds__(256) void gemm_mfma(const unsigned short* __restrict__ Fbu,
                                                 float* __restrict__ S) {
    const __bf16* Fb = (const __bf16*)Fbu;
    const int tid  = threadIdx.x;
    const int wave = tid >> 6;
    const int lane = tid & 63;
    const int row0 = blockIdx.y * 64 + wave * 16;
    const int col0 = blockIdx.x * 64;
    const int lr = lane & 15;         // m (for A) / n (for B) within 16
    const int lk = (lane >> 4) * 8;   // k sub-offset

    const __bf16* pa  = Fb + (size_t)(row0 + lr) * D + lk;
    const __bf16* pb0 = Fb + (size_t)(col0 + lr) * D + lk;
    const __bf16* pb1 = pb0 + 16 * D;
    const __bf16* pb2 = pb0 + 32 * D;
    const __bf16* pb3 = pb0 + 48 * D;

    f32x4 acc0 = {}, acc1 = {}, acc2 = {}, acc3 = {};

    #pragma unroll 4
    for (int k0 = 0; k0 < D; k0 += 32) {
        bf16x8 a  = *(const bf16x8*)(pa  + k0);
        bf16x8 b0 = *(const bf16x8*)(pb0 + k0);
        bf16x8 b1 = *(const bf16x8*)(pb1 + k0);
        bf16x8 b2 = *(const bf16x8*)(pb2 + k0);
        bf16x8 b3 = *(const bf16x8*)(pb3 + k0);
        acc0 = __builtin_amdgcn_mfma_f32_16x16x32_bf16(a, b0, acc0, 0, 0, 0);
        acc1 = __builtin_amdgcn_mfma_f32_16x16x32_bf16(a, b1, acc1, 0, 0, 0);
        acc2 = __builtin_amdgcn_mfma_f32_16x16x32_bf16(a, b2, acc2, 0, 0, 0);
        acc3 = __builtin_amdgcn_mfma_f32_16x16x32_bf16(a, b3, acc3, 0, 0, 0);
    }

    // C/D layout: col = lane&15, row = (lane>>4)*4 + reg
    const int r0 = row0 + (lane >> 4) * 4;
    const int c0 = col0 + lr;
    #pragma unroll
    for (int r = 0; r < 4; ++r) {
        const int rr = r0 + r;
        float* Sr = S + (size_t)rr * N + c0;
        Sr[0]  = (rr == c0     ) ? 1.0f : acc0[r];
        Sr[16] = (rr == c0 + 16) ? 1.0f : acc1[r];
        Sr[32] = (rr == c0 + 32) ? 1.0f : acc2[r];
        Sr[48] = (rr == c0 + 48) ? 1.0f : acc3[r];
    }
}

// ---------------------------------------------------------------------------
// Kernel 2: per-row MS reduction + anchor count + last-block finalize.
// Block = row i, wave w owns classes 4w..4w+3 over all 1024 j.
// ---------------------------------------------------------------------------
__global__ __launch_bounds__(256) void ms_reduce(const float* __restrict__ S,
                                                 const unsigned* __restrict__ mask,
                                                 double* __restrict__ loss_acc,
                                                 int* __restrict__ total,
                                                 unsigned* __restrict__ arrive,
                                                 float* __restrict__ out) {
    const int i    = blockIdx.x;
    const int tid  = threadIdx.x;
    const int lane = tid & 63;
    const int wave = tid >> 6;
    const int cbase = wave * 4;

    float    s[16];
    unsigned mk[16];
    {
        const float4* Srow = (const float4*)(S + (size_t)i * N);
        const uint4*  Mrow = (const uint4*)mask;
        #pragma unroll
        for (int q = 0; q < 4; ++q) {
            float4 v = Srow[lane * 4 + q];
            uint4  m = Mrow[lane * 4 + q];
            s[q * 4 + 0] = v.x; s[q * 4 + 1] = v.y;
            s[q * 4 + 2] = v.z; s[q * 4 + 3] = v.w;
            mk[q * 4 + 0] = m.x; mk[q * 4 + 1] = m.y;
            mk[q * 4 + 2] = m.z; mk[q * 4 + 3] = m.w;
        }
    }

    // ---- pass 1: per-class min_pos / max_neg over this lane's 16 j ----
    float mn[4] = {INFINITY, INFINITY, INFINITY, INFINITY};
    float mx[4] = {-INFINITY, -INFINITY, -INFINITY, -INFINITY};
    #pragma unroll
    for (int u = 0; u < 16; ++u) {
        const float sv = s[u];
        const bool ok1 = sv < 1.0f - EPS_;
        #pragma unroll
        for (int cl = 0; cl < 4; ++cl) {
            const bool pos = (mk[u] >> (cbase + cl)) & 1u;
            mn[cl] = fminf(mn[cl], (pos && ok1) ? sv : INFINITY);
            mx[cl] = fmaxf(mx[cl], pos ? -INFINITY : sv);
        }
    }
    #pragma unroll
    for (int off = 32; off; off >>= 1) {
        #pragma unroll
        for (int cl = 0; cl < 4; ++cl) {
            mn[cl] = fminf(mn[cl], __shfl_xor(mn[cl], off, 64));
            mx[cl] = fmaxf(mx[cl], __shfl_xor(mx[cl], off, 64));
        }
    }
    float mpe[4], mxn[4];
    #pragma unroll
    for (int cl = 0; cl < 4; ++cl) {
        mpe[cl] = (mn[cl] < INFINITY) ? mn[cl] : -INFINITY;
        mxn[cl] = mx[cl];
    }

    // ---- pass 2: selected exp sums ----
    float ps[4] = {}, ns[4] = {};
    #pragma unroll
    for (int u = 0; u < 16; ++u) {
        const float sv = s[u];
        const float ep = expf(-SCALE_POS * (sv - THRESH));
        const float en = expf( SCALE_NEG * (sv - THRESH));
        const bool ok1 = sv < 1.0f - EPS_;
        const float sm = sv - MARGIN;
        const float sp = sv + MARGIN;
        #pragma unroll
        for (int cl = 0; cl < 4; ++cl) {
            const bool pos  = (mk[u] >> (cbase + cl)) & 1u;
            const bool psel = pos && ok1 && (sm < mxn[cl]);
            const bool nsel = (!pos) && (sp > mpe[cl]);
            ps[cl] += psel ? ep : 0.0f;
            ns[cl] += nsel ? en : 0.0f;
        }
    }
    #pragma unroll
    for (int off = 32; off; off >>= 1) {
        #pragma unroll
        for (int cl = 0; cl < 4; ++cl) {
            ps[cl] += __shfl_xor(ps[cl], off, 64);
            ns[cl] += __shfl_xor(ns[cl], off, 64);
        }
    }

    // ---- per-wave loss, block combine, one atomic, last-block finalize ----
    __shared__ double part[4];
    if (lane == 0) {
        const unsigned am = mask[i];
        double lc = 0.0;
        #pragma unroll
        for (int cl = 0; cl < 4; ++cl) {
            const bool anchor = (am >> (cbase + cl)) & 1u;
            if (anchor && ps[cl] > 0.0f && ns[cl] > 0.0f) {
                lc += (double)(log1pf(ps[cl]) * (1.0f / SCALE_POS))
                    + (double)(log1pf(ns[cl]) * (1.0f / SCALE_NEG));
            }
        }
        part[wave] = lc;
    }
    __syncthreads();
    if (tid == 0) {
        atomicAdd(loss_acc, part[0] + part[1] + part[2] + part[3]);
        atomicAdd(total, __popc(mask[i]));
        __threadfence();
        const unsigned old = atomicAdd(arrive, 1u);
        if (old == (unsigned)(N - 1)) {          // last block: finalize
            __threadfence();
            const double L = atomicAdd(loss_acc, 0.0);
            const int    T = atomicAdd(total, 0);
            out[0] = (T > 0) ? (float)(L / (double)T) : 0.0f;
        }
    }
}

// ---------------------------------------------------------------------------
extern "C" void kernel_launch(void* const* d_in, const int* in_sizes, int n_in,
                              void* d_out, int out_size, void* d_ws, size_t ws_size,
                              hipStream_t stream) {
    (void)in_sizes; (void)n_in; (void)out_size; (void)ws_size;
    const float* feats  = (const float*)d_in[0];
    const int*   labels = (const int*)d_in[1];
    float*       out    = (float*)d_out;

    // ws layout: [0,4MB) sim | [4MB,+1MB) bf16 feats | +4KB mask | accums
    char* ws = (char*)d_ws;
    float*          sim  = (float*)ws;
    unsigned short* Fb   = (unsigned short*)(ws + (size_t)N * N * 4);
    unsigned*       mask = (unsigned*)(ws + (size_t)N * N * 4 + (size_t)N * D * 2);
    char* acc_base = ws + (size_t)N * N * 4 + (size_t)N * D * 2 + 4096;
    double*   loss_acc = (double*)acc_base;
    int*      total    = (int*)(acc_base + 8);
    unsigned* arrive   = (unsigned*)(acc_base + 12);

    prep<<<(N * D / 8) / 256, 256, 0, stream>>>(feats, labels, Fb, mask,
                                                loss_acc, total, arrive);
    dim3 gg(N / 64, N / 64);
    gemm_mfma<<<gg, 256, 0, stream>>>(Fb, sim);
    ms_reduce<<<N, 256, 0, stream>>>(sim, mask, loss_acc, total, arrive, out);
}

// Round 4
// 87.795 us; speedup vs baseline: 1.3086x; 1.3086x over previous
//
#include <hip/hip_runtime.h>
#include <math.h>

#define N 1024
#define D 512
#define NC 16

static constexpr float THRESH    = 0.5f;
static constexpr float MARGIN    = 0.1f;
static constexpr float SCALE_POS = 0.05f;
static constexpr float SCALE_NEG = 0.002f;
static constexpr float EPS_      = 1e-5f;

typedef __bf16 bf16x8 __attribute__((ext_vector_type(8)));
typedef float  f32x4  __attribute__((ext_vector_type(4)));
typedef unsigned short ushort8v __attribute__((ext_vector_type(8)));

__device__ __forceinline__ unsigned short f2bf_rne(float x) {
    unsigned u = __builtin_bit_cast(unsigned, x);
    return (unsigned short)((u + 0x7FFFu + ((u >> 16) & 1u)) >> 16);
}

// ---------------------------------------------------------------------------
// Kernel 0: fp32 -> bf16 convert (8/thread) + label bit-pack. No atomics.
// ---------------------------------------------------------------------------
__global__ __launch_bounds__(256) void prep(const float* __restrict__ F,
                                            const int* __restrict__ labels,
                                            unsigned short* __restrict__ Fb,
                                            unsigned* __restrict__ mask) {
    const int idx = blockIdx.x * 256 + threadIdx.x;   // 65536 threads

    const float4* src = (const float4*)F;
    float4 v0 = src[idx * 2];
    float4 v1 = src[idx * 2 + 1];
    ushort8v o;
    o[0] = f2bf_rne(v0.x); o[1] = f2bf_rne(v0.y);
    o[2] = f2bf_rne(v0.z); o[3] = f2bf_rne(v0.w);
    o[4] = f2bf_rne(v1.x); o[5] = f2bf_rne(v1.y);
    o[6] = f2bf_rne(v1.z); o[7] = f2bf_rne(v1.w);
    *(ushort8v*)(Fb + idx * 8) = o;

    if (idx < N) {
        const int4* lp = (const int4*)(labels + idx * NC);
        unsigned m = 0;
        #pragma unroll
        for (int q = 0; q < 4; ++q) {
            int4 l4 = lp[q];
            if (l4.x == 1) m |= 1u << (q * 4 + 0);
            if (l4.y == 1) m |= 1u << (q * 4 + 1);
            if (l4.z == 1) m |= 1u << (q * 4 + 2);
            if (l4.w == 1) m |= 1u << (q * 4 + 3);
        }
        mask[idx] = m;
    }
}

// ---------------------------------------------------------------------------
// Kernel 1: sim = Fb * Fb^T via MFMA bf16, no LDS (both frags load contiguous)
// block: 256 thr = 4 waves; tile 64x64; wave w -> m-strip [16w,16w+16) x 64 n
// Diagonal pinned to 1.0f (fp32 self-sim is excluded by the 1-eps test; bf16
// rounding must not let it sneak back in).
// ---------------------------------------------------------------------------
__global__ __launch_bounds__(256) void gemm_mfma(const unsigned short* __restrict__ Fbu,
                                                 float* __restrict__ S) {
    const __bf16* Fb = (const __bf16*)Fbu;
    const int tid  = threadIdx.x;
    const int wave = tid >> 6;
    const int lane = tid & 63;
    const int row0 = blockIdx.y * 64 + wave * 16;
    const int col0 = blockIdx.x * 64;
    const int lr = lane & 15;         // m (for A) / n (for B) within 16
    const int lk = (lane >> 4) * 8;   // k sub-offset

    const __bf16* pa  = Fb + (size_t)(row0 + lr) * D + lk;
    const __bf16* pb0 = Fb + (size_t)(col0 + lr) * D + lk;
    const __bf16* pb1 = pb0 + 16 * D;
    const __bf16* pb2 = pb0 + 32 * D;
    const __bf16* pb3 = pb0 + 48 * D;

    f32x4 acc0 = {}, acc1 = {}, acc2 = {}, acc3 = {};

    #pragma unroll 4
    for (int k0 = 0; k0 < D; k0 += 32) {
        bf16x8 a  = *(const bf16x8*)(pa  + k0);
        bf16x8 b0 = *(const bf16x8*)(pb0 + k0);
        bf16x8 b1 = *(const bf16x8*)(pb1 + k0);
        bf16x8 b2 = *(const bf16x8*)(pb2 + k0);
        bf16x8 b3 = *(const bf16x8*)(pb3 + k0);
        acc0 = __builtin_amdgcn_mfma_f32_16x16x32_bf16(a, b0, acc0, 0, 0, 0);
        acc1 = __builtin_amdgcn_mfma_f32_16x16x32_bf16(a, b1, acc1, 0, 0, 0);
        acc2 = __builtin_amdgcn_mfma_f32_16x16x32_bf16(a, b2, acc2, 0, 0, 0);
        acc3 = __builtin_amdgcn_mfma_f32_16x16x32_bf16(a, b3, acc3, 0, 0, 0);
    }

    // C/D layout: col = lane&15, row = (lane>>4)*4 + reg
    const int r0 = row0 + (lane >> 4) * 4;
    const int c0 = col0 + lr;
    #pragma unroll
    for (int r = 0; r < 4; ++r) {
        const int rr = r0 + r;
        float* Sr = S + (size_t)rr * N + c0;
        Sr[0]  = (rr == c0     ) ? 1.0f : acc0[r];
        Sr[16] = (rr == c0 + 16) ? 1.0f : acc1[r];
        Sr[32] = (rr == c0 + 32) ? 1.0f : acc2[r];
        Sr[48] = (rr == c0 + 48) ? 1.0f : acc3[r];
    }
}

// ---------------------------------------------------------------------------
// Kernel 2: per-row MS reduction. Block = row i, wave w owns classes 4w..4w+3
// over all 1024 j. NO cross-block atomics / fences: plain store to own slot.
// ---------------------------------------------------------------------------
__global__ __launch_bounds__(256) void ms_reduce(const float* __restrict__ S,
                                                 const unsigned* __restrict__ mask,
                                                 double* __restrict__ partials) {
    const int i    = blockIdx.x;
    const int tid  = threadIdx.x;
    const int lane = tid & 63;
    const int wave = tid >> 6;
    const int cbase = wave * 4;

    float    s[16];
    unsigned mk[16];
    {
        const float4* Srow = (const float4*)(S + (size_t)i * N);
        const uint4*  Mrow = (const uint4*)mask;
        #pragma unroll
        for (int q = 0; q < 4; ++q) {
            float4 v = Srow[lane * 4 + q];
            uint4  m = Mrow[lane * 4 + q];
            s[q * 4 + 0] = v.x; s[q * 4 + 1] = v.y;
            s[q * 4 + 2] = v.z; s[q * 4 + 3] = v.w;
            mk[q * 4 + 0] = m.x; mk[q * 4 + 1] = m.y;
            mk[q * 4 + 2] = m.z; mk[q * 4 + 3] = m.w;
        }
    }

    // ---- pass 1: per-class min_pos / max_neg over this lane's 16 j ----
    float mn[4] = {INFINITY, INFINITY, INFINITY, INFINITY};
    float mx[4] = {-INFINITY, -INFINITY, -INFINITY, -INFINITY};
    #pragma unroll
    for (int u = 0; u < 16; ++u) {
        const float sv = s[u];
        const bool ok1 = sv < 1.0f - EPS_;
        #pragma unroll
        for (int cl = 0; cl < 4; ++cl) {
            const bool pos = (mk[u] >> (cbase + cl)) & 1u;
            mn[cl] = fminf(mn[cl], (pos && ok1) ? sv : INFINITY);
            mx[cl] = fmaxf(mx[cl], pos ? -INFINITY : sv);
        }
    }
    #pragma unroll
    for (int off = 32; off; off >>= 1) {
        #pragma unroll
        for (int cl = 0; cl < 4; ++cl) {
            mn[cl] = fminf(mn[cl], __shfl_xor(mn[cl], off, 64));
            mx[cl] = fmaxf(mx[cl], __shfl_xor(mx[cl], off, 64));
        }
    }
    float mpe[4], mxn[4];
    #pragma unroll
    for (int cl = 0; cl < 4; ++cl) {
        mpe[cl] = (mn[cl] < INFINITY) ? mn[cl] : -INFINITY;
        mxn[cl] = mx[cl];
    }

    // ---- pass 2: selected exp sums ----
    float ps[4] = {}, ns[4] = {};
    #pragma unroll
    for (int u = 0; u < 16; ++u) {
        const float sv = s[u];
        const float ep = __expf(-SCALE_POS * (sv - THRESH));
        const float en = __expf( SCALE_NEG * (sv - THRESH));
        const bool ok1 = sv < 1.0f - EPS_;
        const float sm = sv - MARGIN;
        const float sp = sv + MARGIN;
        #pragma unroll
        for (int cl = 0; cl < 4; ++cl) {
            const bool pos  = (mk[u] >> (cbase + cl)) & 1u;
            const bool psel = pos && ok1 && (sm < mxn[cl]);
            const bool nsel = (!pos) && (sp > mpe[cl]);
            ps[cl] += psel ? ep : 0.0f;
            ns[cl] += nsel ? en : 0.0f;
        }
    }
    #pragma unroll
    for (int off = 32; off; off >>= 1) {
        #pragma unroll
        for (int cl = 0; cl < 4; ++cl) {
            ps[cl] += __shfl_xor(ps[cl], off, 64);
            ns[cl] += __shfl_xor(ns[cl], off, 64);
        }
    }

    // ---- per-wave loss, block combine in LDS, ONE plain store per block ----
    __shared__ double part[4];
    if (lane == 0) {
        const unsigned am = mask[i];
        double lc = 0.0;
        #pragma unroll
        for (int cl = 0; cl < 4; ++cl) {
            const bool anchor = (am >> (cbase + cl)) & 1u;
            if (anchor && ps[cl] > 0.0f && ns[cl] > 0.0f) {
                lc += (double)(log1pf(ps[cl]) * (1.0f / SCALE_POS))
                    + (double)(log1pf(ns[cl]) * (1.0f / SCALE_NEG));
            }
        }
        part[wave] = lc;
    }
    __syncthreads();
    if (tid == 0) {
        partials[i] = part[0] + part[1] + part[2] + part[3];
    }
}

// ---------------------------------------------------------------------------
// Kernel 3: single-block finalize — sum 1024 partials + anchor count from mask
// ---------------------------------------------------------------------------
__global__ __launch_bounds__(256) void finalize(const double* __restrict__ partials,
                                                const unsigned* __restrict__ mask,
                                                float* __restrict__ out) {
    const int tid  = threadIdx.x;
    const int lane = tid & 63;
    const int wave = tid >> 6;

    double s = 0.0;
    int cnt = 0;
    #pragma unroll
    for (int q = 0; q < 4; ++q) {
        s   += partials[tid * 4 + q];
        cnt += __popc(mask[tid * 4 + q]);
    }
    #pragma unroll
    for (int off = 32; off; off >>= 1) {
        s   += __shfl_xor(s, off, 64);
        cnt += __shfl_xor(cnt, off, 64);
    }
    __shared__ double sred[4];
    __shared__ int    cred[4];
    if (lane == 0) { sred[wave] = s; cred[wave] = cnt; }
    __syncthreads();
    if (tid == 0) {
        const double L = sred[0] + sred[1] + sred[2] + sred[3];
        const int    T = cred[0] + cred[1] + cred[2] + cred[3];
        out[0] = (T > 0) ? (float)(L / (double)T) : 0.0f;
    }
}

// ---------------------------------------------------------------------------
extern "C" void kernel_launch(void* const* d_in, const int* in_sizes, int n_in,
                              void* d_out, int out_size, void* d_ws, size_t ws_size,
                              hipStream_t stream) {
    (void)in_sizes; (void)n_in; (void)out_size; (void)ws_size;
    const float* feats  = (const float*)d_in[0];
    const int*   labels = (const int*)d_in[1];
    float*       out    = (float*)d_out;

    // ws layout: [0,4MB) sim | [+1MB) bf16 feats | +4KB mask | 1024 doubles
    char* ws = (char*)d_ws;
    float*          sim      = (float*)ws;
    unsigned short* Fb       = (unsigned short*)(ws + (size_t)N * N * 4);
    unsigned*       mask     = (unsigned*)(ws + (size_t)N * N * 4 + (size_t)N * D * 2);
    double*         partials = (double*)(ws + (size_t)N * N * 4 + (size_t)N * D * 2 + 4096);

    prep<<<(N * D / 8) / 256, 256, 0, stream>>>(feats, labels, Fb, mask);
    dim3 gg(N / 64, N / 64);
    gemm_mfma<<<gg, 256, 0, stream>>>(Fb, sim);
    ms_reduce<<<N, 256, 0, stream>>>(sim, mask, partials);
    finalize<<<1, 256, 0, stream>>>(partials, mask, out);
}